// Round 8
// baseline (81.787 us; speedup 1.0000x reference)
//
#include <hip/hip_runtime.h>
#include <math.h>

#define NFRAMES 16384
#define NJOINTS 22
#define NPATHS  5
#define NPAIRS  (NPATHS * NPATHS)
#define NSEG    16      // segments per motion: 3+3+4+3+3
#define GSTRIDE 32      // padded gli row stride (floats) -> 128B-aligned rows
#define FSTR    (NJOINTS * 3)   // 66 floats per frame per motion
#define FPB     4       // frames per block

typedef float v2f __attribute__((ext_vector_type(2)));

// Per-segment float offsets (joint*3) into a frame: {start, end}.
// path0 (2,5)(5,8)(8,11); path1 (1,4)(4,7)(7,10);
// path2 (3,6)(6,9)(9,12)(12,15); path3 (14,17)(17,19)(19,21);
// path4 (13,16)(16,18)(18,20).
__constant__ int2 c_seg[NSEG] = {
    {6,15},{15,24},{24,33},
    {3,12},{12,21},{21,30},
    {9,18},{18,27},{27,36},{36,45},
    {42,51},{51,57},{57,63},
    {39,48},{48,54},{54,60}
};
__constant__ int c_pstart[NPATHS] = {0, 3, 6, 10, 13};
__constant__ int c_plen[NPATHS]   = {3, 3, 4, 3, 3};

// Packed 2-frame 3-vector: .x/.y/.z are v2f holding {frameA, frameB}.
struct V3 { v2f x, y, z; };
__device__ __forceinline__ V3 vsub(V3 a, V3 b) { V3 r; r.x=a.x-b.x; r.y=a.y-b.y; r.z=a.z-b.z; return r; }
__device__ __forceinline__ v2f vdot(V3 a, V3 b) { return a.x*b.x + a.y*b.y + a.z*b.z; }
__device__ __forceinline__ V3 vcross(V3 a, V3 b) {
    V3 r;
    r.x = a.y*b.z - a.z*b.y;
    r.y = a.z*b.x - a.x*b.z;
    r.z = a.x*b.y - a.y*b.x;
    return r;
}

// asin via A&S 4.4.45 (degree-3): acos(a)=sqrt(1-a)*poly(a), |eps|<=6.7e-5 rad.
__device__ __forceinline__ v2f vfast_asin(v2f x) {
    v2f a = __builtin_elementwise_max(x, -x);   // |x|
    v2f p = a * -0.0187293f + 0.0742610f;
    p = a * p + -0.2121144f;
    p = a * p + 1.5707288f;
    v2f s;
    s.x = __builtin_amdgcn_sqrtf(1.0f - a.x);
    s.y = __builtin_amdgcn_sqrtf(1.0f - a.y);
    v2f r = 1.5707963268f - s * p;
    r.x = (x.x < 0.0f) ? -r.x : r.x;
    r.y = (x.y < 0.0f) ? -r.y : r.y;
    return r;
}

// asin(clamp(d / sqrt(ma*mb))) with jnp safe-normalize semantics
// (zero-norm face -> normalized vec = 0 -> dot 0 -> asin 0)
__device__ __forceinline__ v2f vasin_term(v2f d, v2f ma, v2f mb) {
    v2f m = ma * mb;
    v2f rs;
    rs.x = __builtin_amdgcn_rsqf(m.x);
    rs.y = __builtin_amdgcn_rsqf(m.y);
    v2f one = 1.0f, mone = -1.0f;
    v2f x = __builtin_elementwise_min(one, __builtin_elementwise_max(mone, d * rs));
    v2f r = vfast_asin(x);
    r.x = (ma.x > 0.0f && mb.x > 0.0f) ? r.x : 0.0f;
    r.y = (ma.y > 0.0f && mb.y > 0.0f) ? r.y : 0.0f;
    return r;
}

// Signed GLI terms for one segment pair across 2 packed frames.
// sA/sB: LDS arrays of float4 [coord][frame0..3]; fr = 0 or 2 selects pair.
__device__ __forceinline__ v2f gli_pair2(const float4* __restrict__ sA,
                                         const float4* __restrict__ sB,
                                         int2 o1, int2 o2, int fr) {
    const v2f* A = (const v2f*)sA + fr / 2;   // v2f view: [coord][2*pair + comp]
    const v2f* B = (const v2f*)sB + fr / 2;
    V3 s1; s1.x = A[2*o1.x]; s1.y = A[2*(o1.x+1)]; s1.z = A[2*(o1.x+2)];
    V3 e1; e1.x = A[2*o1.y]; e1.y = A[2*(o1.y+1)]; e1.z = A[2*(o1.y+2)];
    V3 s2; s2.x = B[2*o2.x]; s2.y = B[2*(o2.x+1)]; s2.z = B[2*(o2.x+2)];
    V3 e2; e2.x = B[2*o2.y]; e2.y = B[2*(o2.y+1)]; e2.z = B[2*(o2.y+2)];

    V3 r12 = vsub(e1, s1);
    V3 r13 = vsub(s2, s1);
    V3 r14 = vsub(e2, s1);

    // Faces via 3 crosses:
    //   f0v = r13 x r14, c1 = r12 x r13, c2 = r12 x r14
    //   f1 = c2, f2 = c2 - c1 - f0v, f3 = -c1
    //   sign = dot(cross(r34, r12), r13) = -dot(c2, r13)
    V3 f0v = vcross(r13, r14);
    V3 c1  = vcross(r12, r13);
    V3 c2  = vcross(r12, r14);
    V3 f2  = vsub(vsub(c2, c1), f0v);

    v2f q0 = vdot(f0v, f0v);
    v2f q1 = vdot(c2, c2);
    v2f q2 = vdot(f2, f2);
    v2f q3 = vdot(c1, c1);

    v2f g = vasin_term( vdot(f0v, c2), q0, q1)
          + vasin_term( vdot(c2, f2),  q1, q2)
          + vasin_term(-vdot(f2, c1),  q2, q3)
          + vasin_term(-vdot(c1, f0v), q3, q0);

    v2f sg = -vdot(c2, r13);
    v2f r;
    r.x = (sg.x > 0.0f) ? g.x : -g.x;
    r.y = (sg.y > 0.0f) ? g.y : -g.y;
    return r;
}

// One block (256 threads) per FOUR frames (f0 = 4*blockIdx.x .. f0+3).
//  - LDS holds 4 frames interleaved [coord][frame] (float4) so one
//    ds_read_b128 fetches a coord for all 4 frames
//  - thread t computes the GLI term for segment pair (t>>4, t&15) for all
//    4 frames via two independent packed-fp32 chains (ILP covers rsq/sqrt)
//  - wave w computes frame w's bbox-overlap flag (lanes 0..31: motion1,
//    32..63: motion2; width-32 butterflies + width-64 half-swap)
//  - after the barrier, quarter-wave groups (lanes 0..24, 32..56, 64..88,
//    96..120) bin-reduce frames 0..3 via unrolled padded LDS gathers
__global__ __launch_bounds__(256) void k_gli(const float* __restrict__ m1,
                                             const float* __restrict__ m2,
                                             float* __restrict__ gli,
                                             int* __restrict__ ov) {
    __shared__ float4 sA[FSTR];    // [coord][frame0..3] of motion1
    __shared__ float4 sB[FSTR];
    __shared__ float4 sT[257];     // [term][frame0..3]; sT[256] = 0 pad

    int f0 = blockIdx.x * FPB;
    int t = threadIdx.x;
    const float* a0 = m1 + (size_t)f0 * FSTR;   // 4*66 consecutive floats
    const float* b0 = m2 + (size_t)f0 * FSTR;

    float* sAf = (float*)sA;
    float* sBf = (float*)sB;
    // Stage 528 floats coalesced: t and t+256 cover [0,512), tail 16 by t<16.
    {
        int u = t;                       // [0,256)
        int fr = u / FSTR, co = u - fr * FSTR;
        sAf[4 * co + fr] = a0[u];
        int u2 = t + 256;                // [256,512)
        if (u2 < FPB * FSTR) {
            int fr2 = u2 / FSTR, co2 = u2 - fr2 * FSTR;
            sAf[4 * co2 + fr2] = a0[u2];
        }
        // motion2: same pattern
        int v = t;
        int gr = v / FSTR, cp = v - gr * FSTR;
        sBf[4 * cp + gr] = b0[v];
        int v2 = t + 256;
        if (v2 < FPB * FSTR) {
            int gr2 = v2 / FSTR, cp2 = v2 - gr2 * FSTR;
            sBf[4 * cp2 + gr2] = b0[v2];
        }
        if (t < FPB * FSTR - 512) {      // tail [512,528)
            int u3 = t + 512;
            int fr3 = u3 / FSTR, co3 = u3 - fr3 * FSTR;
            sAf[4 * co3 + fr3] = a0[u3];
            sBf[4 * co3 + fr3] = b0[u3];
        }
    }
    if (t == 0) sT[256] = float4{0.0f, 0.0f, 0.0f, 0.0f};
    __syncthreads();

    int i = t >> 4;
    int j = t & 15;
    int2 o1 = c_seg[i];
    int2 o2 = c_seg[j];
    v2f g01 = gli_pair2(sA, sB, o1, o2, 0);   // frames 0,1
    v2f g23 = gli_pair2(sA, sB, o1, o2, 2);   // frames 2,3
    sT[t] = float4{g01.x, g01.y, g23.x, g23.y};

    // bbox overlap: wave w -> frame w. Lanes 0..31 motion1, 32..63 motion2.
    {
        int w = t >> 6;                  // frame index
        int half = (t >> 5) & 1;         // 0: motion1, 1: motion2
        int jj = t & 31;
        if (jj > NJOINTS - 1) jj = NJOINTS - 1;  // pad lanes replicate joint 21
        const float* p = half ? sBf : sAf;
        float x = p[4 * (jj * 3 + 0) + w];
        float z = p[4 * (jj * 3 + 2) + w];
        float xn = x, xx = x, zn = z, zx = z;
#pragma unroll
        for (int k = 1; k < 32; k <<= 1) {
            xn = fminf(xn, __shfl_xor(xn, k, 32));
            xx = fmaxf(xx, __shfl_xor(xx, k, 32));
            zn = fminf(zn, __shfl_xor(zn, k, 32));
            zx = fmaxf(zx, __shfl_xor(zx, k, 32));
        }
        // swap halves within the wave: pull the other motion's extents
        float oxn = __shfl_xor(xn, 32, 64);
        float oxx = __shfl_xor(xx, 32, 64);
        float ozn = __shfl_xor(zn, 32, 64);
        float ozx = __shfl_xor(zx, 32, 64);
        if ((t & 63) == 0) {
            bool ovx = !((xx < oxn) || (oxx < xn));
            bool ovz = !((zx < ozn) || (ozx < zn));
            ov[f0 + w] = (ovx && ovz) ? 1 : 0;
        }
    }
    __syncthreads();

    // Bin-reduce: lanes 0..24 -> frame0, 32..56 -> frame1, 64..88 -> frame2,
    // 96..120 -> frame3.
    int tt = t & 31;
    int fr = t >> 5;
    if (tt < NPAIRS && (fr & 1) == 0) {
        fr >>= 1;                        // 0..3
        const float* sTf = (const float*)sT;
        int pa = (tt * 205) >> 10;       // tt/5 for tt<25
        int pb = tt - pa * 5;            // tt%5
        int ia0 = c_pstart[pa], na = c_plen[pa];
        int ib0 = c_pstart[pb], nb = c_plen[pb];
        float s = 0.0f;
#pragma unroll
        for (int ka = 0; ka < 4; ka++) {
#pragma unroll
            for (int kb = 0; kb < 4; kb++) {
                int idx = (ka < na && kb < nb) ? ((ia0 + ka) * 16 + (ib0 + kb)) : 256;
                s += sTf[4 * idx + fr];
            }
        }
        gli[(size_t)(f0 + fr) * GSTRIDE + tt] = s * 0.07957747154594767f;  // 1/(4*pi)
    }
}

// out[f] = max_j | gli[f+1][j]*mask[f+1] - gli[f][j]*mask[f] |
// mask[i] = ov[i-1] | ov[i] | ov[i+1]  (out-of-range -> false)
__global__ void k_out(const float* __restrict__ gli, const int* __restrict__ ov,
                      float* __restrict__ out) {
    int f = blockIdx.x * blockDim.x + threadIdx.x;
    if (f >= NFRAMES - 1) return;

    int m0 = ov[f];
    if (f > 0) m0 |= ov[f - 1];
    m0 |= ov[f + 1];

    int m1 = ov[f + 1] | ov[f];
    if (f + 2 <= NFRAMES - 1) m1 |= ov[f + 2];

    float ma = m0 ? 1.0f : 0.0f;
    float mb = m1 ? 1.0f : 0.0f;

    const float4* g0v = (const float4*)(gli + (size_t)f * GSTRIDE);        // 128B-aligned
    const float4* g1v = (const float4*)(gli + (size_t)(f + 1) * GSTRIDE);
    float v = 0.0f;
#pragma unroll
    for (int q = 0; q < 6; q++) {
        float4 u0 = g0v[q];
        float4 u1 = g1v[q];
        v = fmaxf(v, fabsf(u1.x * mb - u0.x * ma));
        v = fmaxf(v, fabsf(u1.y * mb - u0.y * ma));
        v = fmaxf(v, fabsf(u1.z * mb - u0.z * ma));
        v = fmaxf(v, fabsf(u1.w * mb - u0.w * ma));
    }
    {
        float u0 = ((const float*)g0v)[24];
        float u1 = ((const float*)g1v)[24];
        v = fmaxf(v, fabsf(u1 * mb - u0 * ma));
    }
    out[f] = v;
}

extern "C" void kernel_launch(void* const* d_in, const int* in_sizes, int n_in,
                              void* d_out, int out_size, void* d_ws, size_t ws_size,
                              hipStream_t stream) {
    const float* m1 = (const float*)d_in[0];
    const float* m2 = (const float*)d_in[1];
    float* out = (float*)d_out;

    float* gli = (float*)d_ws;                          // NFRAMES*GSTRIDE floats = 2 MB
    int* ov = (int*)(gli + (size_t)NFRAMES * GSTRIDE);  // NFRAMES ints

    k_gli<<<NFRAMES / FPB, 256, 0, stream>>>(m1, m2, gli, ov);

    {
        int threads = 256;
        int blocks = (NFRAMES - 1 + threads - 1) / threads;
        k_out<<<blocks, threads, 0, stream>>>(gli, ov, out);
    }
}

// Round 9
// 79.468 us; speedup vs baseline: 1.0292x; 1.0292x over previous
//
#include <hip/hip_runtime.h>
#include <math.h>

#define NFRAMES 16384
#define NJOINTS 22
#define NPATHS  5
#define NPAIRS  (NPATHS * NPATHS)
#define NSEG    16      // segments per motion: 3+3+4+3+3
#define GSTRIDE 32      // padded gli row stride (floats) -> 128B-aligned rows
#define FSTR    (NJOINTS * 3)   // 66 floats per frame per motion
#define FPB     8       // frames per block (2 per wave, 4 waves)

typedef float v2f __attribute__((ext_vector_type(2)));

// Per-segment float offsets (joint*3) into a frame: {start, end}.
// path0 (2,5)(5,8)(8,11); path1 (1,4)(4,7)(7,10);
// path2 (3,6)(6,9)(9,12)(12,15); path3 (14,17)(17,19)(19,21);
// path4 (13,16)(16,18)(18,20).
__constant__ int2 c_seg[NSEG] = {
    {6,15},{15,24},{24,33},
    {3,12},{12,21},{21,30},
    {9,18},{18,27},{27,36},{36,45},
    {42,51},{51,57},{57,63},
    {39,48},{48,54},{54,60}
};
__constant__ int c_pstart[NPATHS] = {0, 3, 6, 10, 13};
__constant__ int c_plen[NPATHS]   = {3, 3, 4, 3, 3};

// Packed 2-frame 3-vector: .x/.y/.z are v2f holding {frameA, frameB}.
struct V3 { v2f x, y, z; };
__device__ __forceinline__ V3 vsub(V3 a, V3 b) { V3 r; r.x=a.x-b.x; r.y=a.y-b.y; r.z=a.z-b.z; return r; }
__device__ __forceinline__ v2f vdot(V3 a, V3 b) { return a.x*b.x + a.y*b.y + a.z*b.z; }
__device__ __forceinline__ V3 vcross(V3 a, V3 b) {
    V3 r;
    r.x = a.y*b.z - a.z*b.y;
    r.y = a.z*b.x - a.x*b.z;
    r.z = a.x*b.y - a.y*b.x;
    return r;
}

// asin via A&S 4.4.45 (degree-3): acos(a)=sqrt(1-a)*poly(a), |eps|<=6.7e-5 rad.
__device__ __forceinline__ v2f vfast_asin(v2f x) {
    v2f a = __builtin_elementwise_max(x, -x);   // |x|
    v2f p = a * -0.0187293f + 0.0742610f;
    p = a * p + -0.2121144f;
    p = a * p + 1.5707288f;
    v2f s;
    s.x = __builtin_amdgcn_sqrtf(1.0f - a.x);
    s.y = __builtin_amdgcn_sqrtf(1.0f - a.y);
    v2f r = 1.5707963268f - s * p;
    r.x = (x.x < 0.0f) ? -r.x : r.x;
    r.y = (x.y < 0.0f) ? -r.y : r.y;
    return r;
}

// asin(clamp(d / sqrt(ma*mb))) with jnp safe-normalize semantics
// (zero-norm face -> normalized vec = 0 -> dot 0 -> asin 0)
__device__ __forceinline__ v2f vasin_term(v2f d, v2f ma, v2f mb) {
    v2f m = ma * mb;
    v2f rs;
    rs.x = __builtin_amdgcn_rsqf(m.x);
    rs.y = __builtin_amdgcn_rsqf(m.y);
    v2f one = 1.0f, mone = -1.0f;
    v2f x = __builtin_elementwise_min(one, __builtin_elementwise_max(mone, d * rs));
    v2f r = vfast_asin(x);
    r.x = (ma.x > 0.0f && mb.x > 0.0f) ? r.x : 0.0f;
    r.y = (ma.y > 0.0f && mb.y > 0.0f) ? r.y : 0.0f;
    return r;
}

__device__ __forceinline__ v2f shfl_xor_v2(v2f v, int mask, int width) {
    v2f r;
    r.x = __shfl_xor(v.x, mask, width);
    r.y = __shfl_xor(v.y, mask, width);
    return r;
}

// One block (256 threads = 4 waves) per EIGHT frames; wave w owns the packed
// frame pair (f0+2w, f0+2w+1) end-to-end in its private LDS region:
//  - lane-coalesced staging of 2x132 floats into [motion][coord]{fr0,fr1} v2f
//  - lane l computes 4 GLI terms t = l+64k (j = l&15 shared -> motion2
//    fragment loaded once); packed fp32 over the 2 frames
//  - bbox overlap packed over the frame pair via width-32 shuffle
//    butterflies (lanes 0..31: motion1, 32..63: motion2) + width-64 swap
//  - lanes 0..24 bin-reduce via the unrolled padded v2f gather
// Waves never read each other's LDS; the two __syncthreads are balanced.
__global__ __launch_bounds__(256) void k_gli(const float* __restrict__ m1,
                                             const float* __restrict__ m2,
                                             float* __restrict__ gli,
                                             int* __restrict__ ov) {
    __shared__ v2f sF[4][2 * FSTR];   // [wave][motion*66+coord], comps = 2 frames
    __shared__ v2f sT[4][260];        // [wave][term]; [256] = 0 pad

    int t = threadIdx.x;
    int w = t >> 6;
    int l = t & 63;
    int fp = blockIdx.x * FPB + 2 * w;          // first frame of this wave's pair
    const float* a = m1 + (size_t)fp * FSTR;    // 132 consecutive floats (2 frames)
    const float* b = m2 + (size_t)fp * FSTR;

    v2f* sFw = sF[w];
    float* sFf = (float*)sFw;

    // Stage 132 floats per motion: u = l, l+64, (+128 for l<4).
    // float u -> frame fr = u>=66, coord co = u-66*fr; LDS float offset
    // motion1: 2*co+fr, motion2: 132 + 2*co+fr. Stride-2 writes: free 2-way.
    {
        int u1 = l + 64;
        int fr1 = (u1 >= FSTR) ? 1 : 0;
        int co1 = u1 - fr1 * FSTR;
        float a0v = a[l], a1v = a[u1];
        float b0v = b[l], b1v = b[u1];
        sFf[2 * l] = a0v;                       // u0=l: fr=0, co=l
        sFf[2 * co1 + fr1] = a1v;
        sFf[2 * FSTR + 2 * l] = b0v;
        sFf[2 * FSTR + 2 * co1 + fr1] = b1v;
        if (l < 2 * FSTR - 128) {               // u2 = l+128 in [128,132)
            int u2 = l + 128;
            int co2 = u2 - FSTR;                // fr=1
            sFf[2 * co2 + 1] = a[u2];
            sFf[2 * FSTR + 2 * co2 + 1] = b[u2];
        }
        if (l == 32) sT[w][256] = v2f{0.0f, 0.0f};
    }
    __syncthreads();

    // 4 GLI terms per lane: t = l + 64k -> i = (l>>4)+4k, j = l&15 (fixed).
    {
        int j = l & 15;
        int i0 = l >> 4;
        int2 o2 = c_seg[j];
        const v2f* B = sFw + FSTR;
        V3 s2; s2.x = B[o2.x]; s2.y = B[o2.x+1]; s2.z = B[o2.x+2];
        V3 e2; e2.x = B[o2.y]; e2.y = B[o2.y+1]; e2.z = B[o2.y+2];
        V3 r34 = vsub(e2, s2);
        for (int k = 0; k < 4; k++) {
            int2 o1 = c_seg[i0 + 4 * k];
            V3 s1; s1.x = sFw[o1.x]; s1.y = sFw[o1.x+1]; s1.z = sFw[o1.x+2];
            V3 e1; e1.x = sFw[o1.y]; e1.y = sFw[o1.y+1]; e1.z = sFw[o1.y+2];

            V3 r12 = vsub(e1, s1);
            V3 r13 = vsub(s2, s1);
            V3 r14 = vsub(e2, s1);

            // f0v = r13 x r14, c1 = r12 x r13, c2 = r12 x r14
            // faces: f0v, c2, c2-c1-f0v, -c1; sign = -dot(c2, r13)
            V3 f0v = vcross(r13, r14);
            V3 c1  = vcross(r12, r13);
            V3 c2  = vcross(r12, r14);
            V3 f2  = vsub(vsub(c2, c1), f0v);

            v2f q0 = vdot(f0v, f0v);
            v2f q1 = vdot(c2, c2);
            v2f q2 = vdot(f2, f2);
            v2f q3 = vdot(c1, c1);

            v2f g = vasin_term( vdot(f0v, c2), q0, q1)
                  + vasin_term( vdot(c2, f2),  q1, q2)
                  + vasin_term(-vdot(f2, c1),  q2, q3)
                  + vasin_term(-vdot(c1, f0v), q3, q0);

            v2f sg = -vdot(c2, r13);
            v2f res;
            res.x = (sg.x > 0.0f) ? g.x : -g.x;
            res.y = (sg.y > 0.0f) ? g.y : -g.y;
            sT[w][l + 64 * k] = res;
        }
        (void)r34;
    }

    // bbox overlap, packed over the frame pair.
    {
        int half = l >> 5;                   // 0: motion1, 1: motion2
        int jj = l & 31;
        if (jj > NJOINTS - 1) jj = NJOINTS - 1;  // pad lanes replicate joint 21
        const v2f* p = sFw + half * FSTR;
        v2f x = p[jj * 3 + 0];
        v2f z = p[jj * 3 + 2];
        v2f xn = x, xx = x, zn = z, zx = z;
#pragma unroll
        for (int k = 1; k < 32; k <<= 1) {
            xn = __builtin_elementwise_min(xn, shfl_xor_v2(xn, k, 32));
            xx = __builtin_elementwise_max(xx, shfl_xor_v2(xx, k, 32));
            zn = __builtin_elementwise_min(zn, shfl_xor_v2(zn, k, 32));
            zx = __builtin_elementwise_max(zx, shfl_xor_v2(zx, k, 32));
        }
        v2f oxn = shfl_xor_v2(xn, 32, 64);
        v2f oxx = shfl_xor_v2(xx, 32, 64);
        v2f ozn = shfl_xor_v2(zn, 32, 64);
        v2f ozx = shfl_xor_v2(zx, 32, 64);
        if (l == 0) {
            int2 o;
            bool vx0 = !((xx.x < oxn.x) || (oxx.x < xn.x));
            bool vz0 = !((zx.x < ozn.x) || (ozx.x < zn.x));
            bool vx1 = !((xx.y < oxn.y) || (oxx.y < xn.y));
            bool vz1 = !((zx.y < ozn.y) || (ozx.y < zn.y));
            o.x = (vx0 && vz0) ? 1 : 0;
            o.y = (vx1 && vz1) ? 1 : 0;
            *(int2*)(ov + fp) = o;          // fp is even -> 8B aligned
        }
    }
    __syncthreads();

    // Bin-reduce: lanes 0..24 of each wave, packed over the frame pair.
    if (l < NPAIRS) {
        int pa = (l * 205) >> 10;   // l/5 for l<25
        int pb = l - pa * 5;        // l%5
        int ia0 = c_pstart[pa], na = c_plen[pa];
        int ib0 = c_pstart[pb], nb = c_plen[pb];
        v2f s = v2f{0.0f, 0.0f};
#pragma unroll
        for (int ka = 0; ka < 4; ka++) {
#pragma unroll
            for (int kb = 0; kb < 4; kb++) {
                int idx = (ka < na && kb < nb) ? ((ia0 + ka) * 16 + (ib0 + kb)) : 256;
                s += sT[w][idx];
            }
        }
        s *= 0.07957747154594767f;  // 1/(4*pi)
        gli[(size_t)fp * GSTRIDE + l] = s.x;
        gli[(size_t)(fp + 1) * GSTRIDE + l] = s.y;
    }
}

// out[f] = max_j | gli[f+1][j]*mask[f+1] - gli[f][j]*mask[f] |
// mask[i] = ov[i-1] | ov[i] | ov[i+1]  (out-of-range -> false)
__global__ void k_out(const float* __restrict__ gli, const int* __restrict__ ov,
                      float* __restrict__ out) {
    int f = blockIdx.x * blockDim.x + threadIdx.x;
    if (f >= NFRAMES - 1) return;

    int m0 = ov[f];
    if (f > 0) m0 |= ov[f - 1];
    m0 |= ov[f + 1];

    int m1 = ov[f + 1] | ov[f];
    if (f + 2 <= NFRAMES - 1) m1 |= ov[f + 2];

    float ma = m0 ? 1.0f : 0.0f;
    float mb = m1 ? 1.0f : 0.0f;

    const float4* g0v = (const float4*)(gli + (size_t)f * GSTRIDE);        // 128B-aligned
    const float4* g1v = (const float4*)(gli + (size_t)(f + 1) * GSTRIDE);
    float v = 0.0f;
#pragma unroll
    for (int q = 0; q < 6; q++) {
        float4 u0 = g0v[q];
        float4 u1 = g1v[q];
        v = fmaxf(v, fabsf(u1.x * mb - u0.x * ma));
        v = fmaxf(v, fabsf(u1.y * mb - u0.y * ma));
        v = fmaxf(v, fabsf(u1.z * mb - u0.z * ma));
        v = fmaxf(v, fabsf(u1.w * mb - u0.w * ma));
    }
    {
        float u0 = ((const float*)g0v)[24];
        float u1 = ((const float*)g1v)[24];
        v = fmaxf(v, fabsf(u1 * mb - u0 * ma));
    }
    out[f] = v;
}

extern "C" void kernel_launch(void* const* d_in, const int* in_sizes, int n_in,
                              void* d_out, int out_size, void* d_ws, size_t ws_size,
                              hipStream_t stream) {
    const float* m1 = (const float*)d_in[0];
    const float* m2 = (const float*)d_in[1];
    float* out = (float*)d_out;

    float* gli = (float*)d_ws;                          // NFRAMES*GSTRIDE floats = 2 MB
    int* ov = (int*)(gli + (size_t)NFRAMES * GSTRIDE);  // NFRAMES ints

    k_gli<<<NFRAMES / FPB, 256, 0, stream>>>(m1, m2, gli, ov);

    {
        int threads = 256;
        int blocks = (NFRAMES - 1 + threads - 1) / threads;
        k_out<<<blocks, threads, 0, stream>>>(gli, ov, out);
    }
}